// Round 8
// baseline (397.270 us; speedup 1.0000x reference)
//
#include <hip/hip_runtime.h>

// Problem constants (fixed by reference setup_inputs)
#define BN 32768      // batch
#define DN 1024       // feature dim
#define CN 256        // num classes
#define RCAP 512      // absolute max class size tracked (for k_corr bookkeeping)
#define NSLICE 16     // column slices of 64 floats
#define NCHUNK 16     // row chunks of 2048 rows
#define RPB (BN / NCHUNK)   // 2048 rows per scatter block

__device__ __forceinline__ float dot4(float4 a, float4 b) {
    return a.x*b.x + a.y*b.y + a.z*b.z + a.w*b.w;
}

// ---------------------------------------------------------------------------
// KC: per-class ordered compaction + counts (+ acc zero). One block (256 thr)
// per class. Labels staged into LDS packed as bytes (32 KB); 4 waves scan 1/4
// each: count pass -> wave prefix -> write pass. Only k_corr consumes idx.
// ---------------------------------------------------------------------------
__global__ void __launch_bounds__(256) kc_compact(const int* __restrict__ labels,
                                                  int* __restrict__ idx,
                                                  int* __restrict__ counts,
                                                  float* __restrict__ acc) {
    __shared__ unsigned int packed[BN / 4];   // 32 KB: 4 labels per word
    __shared__ int wcnt[4];
    const int c = blockIdx.x;
    const int t = threadIdx.x;

    for (int w = t; w < BN / 4; w += 256) {
        const int4 v = ((const int4*)labels)[w];
        packed[w] = (unsigned int)(v.x & 255)
                  | ((unsigned int)(v.y & 255) << 8)
                  | ((unsigned int)(v.z & 255) << 16)
                  | ((unsigned int)(v.w & 255) << 24);
    }
    __syncthreads();

    const int wave = t >> 6, lane = t & 63;
    const unsigned long long lt = (lane == 0) ? 0ull : (~0ull >> (64 - lane));
    const int ch0 = wave * 128, ch1 = ch0 + 128;

    int cnt = 0;
    for (int ch = ch0; ch < ch1; ++ch) {
        const int gi = ch * 64 + lane;
        const int lab = (packed[gi >> 2] >> ((gi & 3) * 8)) & 255;
        cnt += __popcll(__ballot(lab == c));
    }
    if (lane == 0) wcnt[wave] = cnt;
    __syncthreads();

    int base = 0;
    for (int w2 = 0; w2 < wave; ++w2) base += wcnt[w2];

    for (int ch = ch0; ch < ch1; ++ch) {
        const int gi = ch * 64 + lane;
        const int lab = (packed[gi >> 2] >> ((gi & 3) * 8)) & 255;
        const bool pred = (lab == c);
        const unsigned long long mask = __ballot(pred);
        if (pred) {
            const int pos = base + __popcll(mask & lt);
            if (pos < RCAP) idx[c * RCAP + pos] = gi;
        }
        base += __popcll(mask);
    }
    if (t == 0) {
        counts[c] = wcnt[0] + wcnt[1] + wcnt[2] + wcnt[3];
        if (c == 0) *acc = 0.0f;
    }
}

// ---------------------------------------------------------------------------
// K_RNORM: per-row inverse norm. One wave per row, 4 rows per block.
// Pure sequential streaming, fully coalesced; 8192 blocks saturate.
// ---------------------------------------------------------------------------
__global__ void __launch_bounds__(256) k_rnorm(const float4* __restrict__ x4,
                                               float* __restrict__ rnorm) {
    const int wave = threadIdx.x >> 6;
    const int lane = threadIdx.x & 63;
    const int row = blockIdx.x * 4 + wave;
    const float4* base = x4 + (size_t)row * (DN / 4);
    const float4 v0 = base[lane];
    const float4 v1 = base[lane + 64];
    const float4 v2 = base[lane + 128];
    const float4 v3 = base[lane + 192];
    float ss = dot4(v0, v0) + dot4(v1, v1) + dot4(v2, v2) + dot4(v3, v3);
#pragma unroll
    for (int off = 32; off; off >>= 1) ss += __shfl_xor(ss, off, 64);
    if (lane == 0) rnorm[row] = 1.0f / fmaxf(sqrtf(ss), 1e-12f);
}

// ---------------------------------------------------------------------------
// K_SCATTER: class sums by scatter-streaming (NO row gather). Grid =
// NCHUNK x NSLICE = 256 blocks x 1024 thr. Block (chunk, slice) streams rows
// [chunk*2048, chunk*2048+2048), columns [slice*64, slice*64+64), holding ALL
// 256 class accumulators for its slice in LDS (64 KB). Per row per wave:
// one coalesced global_load_dword (256 B, sequential 4 KB-stride walk) + one
// ds_add_f32 (lanes hit consecutive LDS addrs = 2/bank = conflict-free).
// Zero cross-lane ops, zero dependent addresses, 8-row unroll -> max MLP.
// Per-block partial (16 KB) written coalesced; k_red combines.
// ---------------------------------------------------------------------------
__global__ void __launch_bounds__(1024) k_scatter(const float* __restrict__ x,
                                                  const int* __restrict__ labels,
                                                  const float* __restrict__ rnorm,
                                                  float* __restrict__ partials) {
    __shared__ float cacc[CN * 64];   // 64 KB: per-class accumulators, this slice
    __shared__ int   slab[RPB];       // 8 KB: labels of this chunk
    __shared__ float srn[RPB];        // 8 KB: rnorms of this chunk
    const int b = blockIdx.x;
    const int slice = b & (NSLICE - 1);
    const int chunk = b >> 4;
    const int t = threadIdx.x;
    const int wave = t >> 6, lane = t & 63;
    const int r0 = chunk * RPB;

    for (int i = t; i < CN * 64; i += 1024) cacc[i] = 0.0f;
    for (int i = t; i < RPB; i += 1024) {
        slab[i] = labels[r0 + i];
        srn[i]  = rnorm[r0 + i];
    }
    __syncthreads();

    // wave handles 128 consecutive rows of the chunk
    const float* colbase = x + (size_t)r0 * DN + slice * 64 + lane;
    const int wr0 = wave * (RPB / 16);
    for (int i = 0; i < RPB / 16; i += 8) {
        const int rr = wr0 + i;
        const int   l0 = slab[rr + 0], l1 = slab[rr + 1], l2 = slab[rr + 2], l3 = slab[rr + 3];
        const int   l4 = slab[rr + 4], l5 = slab[rr + 5], l6 = slab[rr + 6], l7 = slab[rr + 7];
        const float r0f = srn[rr + 0], r1f = srn[rr + 1], r2f = srn[rr + 2], r3f = srn[rr + 3];
        const float r4f = srn[rr + 4], r5f = srn[rr + 5], r6f = srn[rr + 6], r7f = srn[rr + 7];
        const float v0 = colbase[(size_t)(rr + 0) * DN];
        const float v1 = colbase[(size_t)(rr + 1) * DN];
        const float v2 = colbase[(size_t)(rr + 2) * DN];
        const float v3 = colbase[(size_t)(rr + 3) * DN];
        const float v4 = colbase[(size_t)(rr + 4) * DN];
        const float v5 = colbase[(size_t)(rr + 5) * DN];
        const float v6 = colbase[(size_t)(rr + 6) * DN];
        const float v7 = colbase[(size_t)(rr + 7) * DN];
        atomicAdd(&cacc[l0 * 64 + lane], v0 * r0f);
        atomicAdd(&cacc[l1 * 64 + lane], v1 * r1f);
        atomicAdd(&cacc[l2 * 64 + lane], v2 * r2f);
        atomicAdd(&cacc[l3 * 64 + lane], v3 * r3f);
        atomicAdd(&cacc[l4 * 64 + lane], v4 * r4f);
        atomicAdd(&cacc[l5 * 64 + lane], v5 * r5f);
        atomicAdd(&cacc[l6 * 64 + lane], v6 * r6f);
        atomicAdd(&cacc[l7 * 64 + lane], v7 * r7f);
    }
    __syncthreads();

    float* pb = partials + (size_t)b * (CN * 64);
    for (int i = t; i < CN * 64; i += 1024) pb[i] = cacc[i];
}

// ---------------------------------------------------------------------------
// K_RED: one block (256 thr) per class: for each col j, sum the 16 chunk
// partials (coalesced: a wave's 64 threads span one slice) -> sums[c],
// snorm2[c] = ||S||^2, closed-form class contribution added to acc.
// partials layout: block b = chunk*16 + slice owns [b][class][64].
// ---------------------------------------------------------------------------
__global__ void __launch_bounds__(256) k_red(const float* __restrict__ partials,
                                             const int* __restrict__ counts,
                                             float* __restrict__ sums,
                                             float* __restrict__ snorm2,
                                             float* __restrict__ acc) {
    __shared__ float wred[4];
    const int c = blockIdx.x;
    const int t = threadIdx.x;
    const int wave = t >> 6, lane = t & 63;

    float d = 0.0f;
#pragma unroll
    for (int jj = 0; jj < 4; ++jj) {
        const int j = t + jj * 256;
        const int slice = j >> 6, col = j & 63;
        float tot = 0.0f;
#pragma unroll
        for (int ch = 0; ch < NCHUNK; ++ch) {
            tot += partials[(size_t)((ch * NSLICE + slice) * CN + c) * 64 + col];
        }
        sums[(size_t)c * DN + j] = tot;
        d += tot * tot;
    }
#pragma unroll
    for (int off = 32; off; off >>= 1) d += __shfl_xor(d, off, 64);
    if (lane == 0) wred[wave] = d;
    __syncthreads();
    if (t == 0) {
        const float s2 = wred[0] + wred[1] + wred[2] + wred[3];
        snorm2[c] = s2;
        const int n = counts[c];
        if (n > 1) {
            const float nf = (float)n;
            atomicAdd(acc, (nf - s2 / nf) * (1.0f / DN));
        }
    }
}

// ---------------------------------------------------------------------------
// K_CORR: exclusion corrections. Row i has exclusion iff i < counts[labels[i]]
// (~128-170 rows). delta = corrected - naive dist; ||f_i||^2 cancels.
// One 256-thread block per candidate row i in [0, RCAP).
// ---------------------------------------------------------------------------
__global__ void __launch_bounds__(256) k_corr(const float4* __restrict__ x4,
                                              const int* __restrict__ labels,
                                              const int* __restrict__ counts,
                                              const int* __restrict__ idx,
                                              const float* __restrict__ rnorm,
                                              const float* __restrict__ sums,
                                              const float* __restrict__ snorm2,
                                              float* __restrict__ acc) {
    const int i = blockIdx.x;
    const int c = labels[i];
    const int n = counts[c];
    if (i >= n || n < 2 || i >= RCAP) return;  // no exclusion or contrib==0
    const int k = idx[c * RCAP + i];
    const int t = threadIdx.x;

    const float4 xi = x4[(size_t)i * 256 + t];
    const float4 xk = x4[(size_t)k * 256 + t];
    const float4 s  = ((const float4*)sums)[(size_t)c * 256 + t];

    float d0 = dot4(xi, s);
    float d1 = dot4(xi, xk);
    float d2 = dot4(xk, s);
    float d3 = dot4(xk, xk);
#pragma unroll
    for (int off = 32; off; off >>= 1) {
        d0 += __shfl_xor(d0, off, 64);
        d1 += __shfl_xor(d1, off, 64);
        d2 += __shfl_xor(d2, off, 64);
        d3 += __shfl_xor(d3, off, 64);
    }
    __shared__ float4 wred[4];
    if ((t & 63) == 0) wred[t >> 6] = make_float4(d0, d1, d2, d3);
    __syncthreads();
    if (t == 0) {
        const float xiS  = wred[0].x + wred[1].x + wred[2].x + wred[3].x;
        const float xixk = wred[0].y + wred[1].y + wred[2].y + wred[3].y;
        const float xkS  = wred[0].z + wred[1].z + wred[2].z + wred[3].z;
        const float xkxk = wred[0].w + wred[1].w + wred[2].w + wred[3].w;
        const float rni = rnorm[i], rnk = rnorm[k], s2 = snorm2[c];
        const float fiS  = rni * xiS;
        const float fifk = rni * rnk * xixk;
        const float Sfk  = rnk * xkS;
        const float fk2  = rnk * rnk * xkxk;
        const float nf = (float)n;
        const float dd = nf - 1.0f;
        const float naive = -2.0f * fiS / nf + s2 / (nf * nf);
        const float corr  = -2.0f * (fiS - fifk) / dd + (s2 - 2.0f * Sfk + fk2) / (dd * dd);
        atomicAdd(acc, (corr - naive) * (1.0f / DN));
    }
}

// ---------------------------------------------------------------------------
// K_FIN: finalize scalar output
// ---------------------------------------------------------------------------
__global__ void k_fin(const float* __restrict__ acc, float* __restrict__ out) {
    out[0] = (0.0005f / (float)BN) * acc[0];
}

extern "C" void kernel_launch(void* const* d_in, const int* in_sizes, int n_in,
                              void* d_out, int out_size, void* d_ws, size_t ws_size,
                              hipStream_t stream) {
    const float* features = (const float*)d_in[0];
    const int* labels = (const int*)d_in[1];
    float* out = (float*)d_out;

    // ws layout (bytes):
    char* ws = (char*)d_ws;
    float* partials = (float*)(ws + 0);                // 256 blk * 16 KB = 16 MiB
    float* rnorm    = (float*)(ws + 16777216);         // 32768 f   -> 16908288
    float* sums     = (float*)(ws + 16908288);         // 262144 f  -> 17956864
    int*   idx      = (int*)  (ws + 17956864);         // 256*512 i -> 18481152
    int*   counts   = (int*)  (ws + 18481152);         // 256 i     -> 18482176
    float* snorm2   = (float*)(ws + 18482176);         // 256 f     -> 18483200
    float* acc      = (float*)(ws + 18483200);         // 1 f

    const float4* x4 = (const float4*)features;

    kc_compact<<<CN, 256, 0, stream>>>(labels, idx, counts, acc);
    k_rnorm<<<BN / 4, 256, 0, stream>>>(x4, rnorm);
    k_scatter<<<NCHUNK * NSLICE, 1024, 0, stream>>>(features, labels, rnorm, partials);
    k_red<<<CN, 256, 0, stream>>>(partials, counts, sums, snorm2, acc);
    k_corr<<<RCAP, 256, 0, stream>>>(x4, labels, counts, idx, rnorm, sums, snorm2, acc);
    k_fin<<<1, 1, 0, stream>>>(acc, out);
}